// Round 15
// baseline (207.434 us; speedup 1.0000x reference)
//
#include <hip/hip_runtime.h>

#define B_N 4096
#define C_N 128
#define E_N 10

#define NM3 165
#define NM2 45
#define NMT 219           // dense s: deg1 0..8, deg2 9..53, deg3 54..218
#define TSTRIDE 240       // float4 stride per (e,c) table (3840 B)
// 64B-aligned section starts (float4 units) in the padded table:
#define MOFF1 0           // deg1: 0..8
#define MOFF2 12          // deg2: 12..56  (45)
#define MOFF3 60          // deg3: 60..224 (165)

// Usym float-offsets (relative to usym base in ws)
#define OFF_S3 0          // [165][23]
#define OFF_V3 3795       // [165][3][15]
#define OFF_S2 11220      // [45][3]
#define OFF_V2 11355      // [45][12]
#define USYM_FLOATS 11895
#define SYMU_BLOCKS 47    // ceil(11895/256)

// ws byte offsets
#define WS_CNT    0
#define WS_LIST   64
#define WS_USYM   (64 + B_N * E_N * 4)            // 163904
#define WS_TABLES 212992                           // 1024-aligned
// tables bytes: 1280 * 240 * 16 = 4,915,200

__device__ __forceinline__ void unrank3(int m, int& I, int& J, int& K) {
    int n = 0;
    for (int i = 0; i < 9; ++i)
        for (int j = i; j < 9; ++j)
            for (int k = j; k < 9; ++k) {
                if (n == m) { I = i; J = j; K = k; return; }
                ++n;
            }
}
__device__ __forceinline__ void unrank2(int m, int& I, int& J) {
    int n = 0;
    for (int i = 0; i < 9; ++i)
        for (int j = i; j < 9; ++j) {
            if (n == m) { I = i; J = j; return; }
            ++n;
        }
}

// ---------------------------------------------------------------------------
// Kernel 1 (merged prep): blocks 0..15 bucket nodes by element; blocks
// 16..62 symmetrize U into the monomial basis. One launch instead of two.
// ---------------------------------------------------------------------------
__global__ __launch_bounds__(256) void prep_kernel(
    const float* __restrict__ y, int* __restrict__ cnt, int* __restrict__ list,
    const float* __restrict__ U3s, const float* __restrict__ U2s,
    const float* __restrict__ U3v, const float* __restrict__ U2v,
    float* __restrict__ us)
{
    const int blk = blockIdx.x;
    const int tid = threadIdx.x;
    if (blk < 16) {
        int b = blk * 256 + tid;
        if (b >= B_N) return;
        const float* yb = y + (size_t)b * E_N;
        int e = 0;
#pragma unroll
        for (int j = 1; j < E_N; ++j) e = (yb[j] > 0.5f) ? j : e;
        int pos = atomicAdd(&cnt[e], 1);
        list[e * B_N + pos] = b;
        return;
    }
    int t = (blk - 16) * 256 + tid;
    if (t < 3795) {                      // S3: [165][23]
        int m = t / 23, kk = t - m * 23;
        int i, j, k; unrank3(m, i, j, k);
        float sc = (i == k) ? (1.f / 6.f) : ((i == j || j == k) ? 0.5f : 1.f);
#define U3S(a,b,cc) U3s[(((a)*9+(b))*9+(cc))*23 + kk]
        float v = U3S(i,j,k) + U3S(i,k,j) + U3S(j,i,k) + U3S(j,k,i) + U3S(k,i,j) + U3S(k,j,i);
        us[OFF_S3 + m * 23 + kk] = v * sc;
    } else if (t < 11220) {              // V3: [165][3][15]
        int r = t - 3795;
        int m = r / 45, q = r - m * 45;
        int a = q / 15, kk = q - a * 15;
        int i, j, k; unrank3(m, i, j, k);
        float sc = (i == k) ? (1.f / 6.f) : ((i == j || j == k) ? 0.5f : 1.f);
#define U3V(p,b,cc) U3v[((((a)*9+(p))*9+(b))*9+(cc))*15 + kk]
        float v = U3V(i,j,k) + U3V(i,k,j) + U3V(j,i,k) + U3V(j,k,i) + U3V(k,i,j) + U3V(k,j,i);
        us[OFF_V3 + m * 45 + a * 15 + kk] = v * sc;
    } else if (t < 11355) {              // S2: [45][3]
        int r = t - 11220;
        int m = r / 3, kk = r - m * 3;
        int i, j; unrank2(m, i, j);
        float sc = (i == j) ? 0.5f : 1.f;
        us[OFF_S2 + m * 3 + kk] =
            (U2s[(i * 9 + j) * 3 + kk] + U2s[(j * 9 + i) * 3 + kk]) * sc;
    } else if (t < USYM_FLOATS) {        // V2: [45][12]
        int r = t - 11355;
        int m = r / 12, q = r - m * 12;
        int a = q / 4, kk = q - a * 4;
        int i, j; unrank2(m, i, j);
        float sc = (i == j) ? 0.5f : 1.f;
        us[OFF_V2 + m * 12 + a * 4 + kk] =
            (U2v[((a * 9 + i) * 9 + j) * 4 + kk] + U2v[((a * 9 + j) * 9 + i) * 4 + kk]) * sc;
    }
}

// ---------------------------------------------------------------------------
// Kernel 2: build per-(e,c) monomial coefficient tables in GLOBAL ws.
// Grid (m=219, e=10) x 128 threads (c): usym reads are block-uniform
// (s_load), W reads coalesced across lanes -- much better than the old
// per-thread-scattered-usym layout. Padded table: sections at MOFF1/2/3
// (64B-aligned) for s_load merging in the SMEM-variant main blocks.
// ---------------------------------------------------------------------------
__global__ __launch_bounds__(128) void build_tables_kernel(
    const float* __restrict__ usym,
    const float* __restrict__ U1s, const float* __restrict__ U1v,
    const float* __restrict__ W1s, const float* __restrict__ W2s, const float* __restrict__ W3s,
    const float* __restrict__ W1v, const float* __restrict__ W2v, const float* __restrict__ W3v,
    float* __restrict__ tables)
{
    const int m = blockIdx.x;   // 0..218 (dense index)
    const int e = blockIdx.y;   // 0..9
    const int c = threadIdx.x;  // 0..127

    float4 t;
    int moff;
    if (m < 9) {
        moff = MOFF1 + m;
        t.x = U1s[m]      * W1s[e * C_N + c];
        t.y = U1v[m]      * W1v[e * C_N + c];
        t.z = U1v[9 + m]  * W1v[e * C_N + c];
        t.w = U1v[18 + m] * W1v[e * C_N + c];
    } else if (m < 9 + NM2) {
        const int mm = m - 9;
        moff = MOFF2 + mm;
        float s = 0.f;
#pragma unroll
        for (int k = 0; k < 3; ++k)
            s = fmaf(usym[OFF_S2 + mm * 3 + k], W2s[(e * 3 + k) * C_N + c], s);
        t.x = s;
        float tv[3];
#pragma unroll
        for (int a = 0; a < 3; ++a) {
            float sv = 0.f;
#pragma unroll
            for (int k = 0; k < 4; ++k)
                sv = fmaf(usym[OFF_V2 + mm * 12 + a * 4 + k], W2v[(e * 4 + k) * C_N + c], sv);
            tv[a] = sv;
        }
        t.y = tv[0]; t.z = tv[1]; t.w = tv[2];
    } else {
        const int mm = m - (9 + NM2);
        moff = MOFF3 + mm;
        float s = 0.f;
#pragma unroll
        for (int k = 0; k < 23; ++k)
            s = fmaf(usym[OFF_S3 + mm * 23 + k], W3s[(e * 23 + k) * C_N + c], s);
        t.x = s;
        float tv[3];
#pragma unroll
        for (int a = 0; a < 3; ++a) {
            float sv = 0.f;
#pragma unroll
            for (int k = 0; k < 15; ++k)
                sv = fmaf(usym[OFF_V3 + mm * 45 + a * 15 + k], W3v[(e * 15 + k) * C_N + c], sv);
            tv[a] = sv;
        }
        t.y = tv[0]; t.z = tv[1]; t.w = tv[2];
    }
    ((float4*)tables)[(size_t)(e * C_N + c) * TSTRIDE + moff] = t;
}

// ---------------------------------------------------------------------------
// Kernel 3: main contraction -- VARIANT-PER-BLOCK dual pipe. Even-c blocks
// run the pure SMEM walk (R9-proven: uniform pointer, ascending sections,
// merged s_load -> SGPR); odd-c blocks run the pure LDS walk (R11-proven:
// staged b32 SoA same-address broadcasts). ~50/50 mix of blocks per CU puts
// the scalar path and the LDS pipe to work CONCURRENTLY (R14 showed the
// within-wave split serializes phases). Branch is block-uniform; NB=1 (the
// only non-spilling width).
// ---------------------------------------------------------------------------
__global__ __launch_bounds__(256) void sc_main_kernel(
    const float* __restrict__ x,
    const int* __restrict__ cnt, const int* __restrict__ list,
    const float* __restrict__ tables,
    float* __restrict__ out)
{
    const int c     = blockIdx.x;   // 0..127
    const int e     = blockIdx.y;   // 0..9
    const int chunk = blockIdx.z;   // 0..3

    const int n = cnt[e];
    if (chunk * 256 >= n) return;   // block-uniform exit (pre-barrier)

    __shared__ float Tx[NMT], Ty[NMT], Tz[NMT], Tw[NMT];
    const int tid = threadIdx.x;

    const float4* __restrict__ T =
        (const float4*)tables + (size_t)(e * C_N + c) * TSTRIDE;   // block-uniform

    const bool use_lds = (c & 1) != 0;
    if (use_lds) {
        if (tid < NMT) {
            int moff = tid < 9 ? (MOFF1 + tid)
                     : (tid < 54 ? (MOFF2 + tid - 9) : (MOFF3 + tid - 54));
            float4 t = T[moff];
            Tx[tid] = t.x; Ty[tid] = t.y; Tz[tid] = t.z; Tw[tid] = t.w;
        }
        __syncthreads();
    }

    const int idx = chunk * 256 + tid;
    if (idx >= n) return;           // no barriers after this point
    const int b = list[e * B_N + idx];

    const float* xp = x + ((size_t)b * C_N + c) * 9;
    float xr[9];
#pragma unroll
    for (int i = 0; i < 9; ++i) xr[i] = xp[i];

    float ax = 0.f, ay = 0.f, az = 0.f, aw = 0.f;

    if (!use_lds) {
        // ======== SMEM variant (R9 walk) ========
#pragma unroll
        for (int i = 0; i < 9; ++i) {
            float4 t = T[MOFF1 + i];
            float q = xr[i];
            ax = fmaf(t.x, q, ax);
            ay = fmaf(t.y, q, ay);
            az = fmaf(t.z, q, az);
            aw = fmaf(t.w, q, aw);
        }
        int m2 = MOFF2;
#pragma unroll
        for (int i = 0; i < 9; ++i) {
#pragma unroll
            for (int j = i; j < 9; ++j) {
                float4 t = T[m2++];
                float p = xr[i] * xr[j];
                ax = fmaf(t.x, p, ax);
                ay = fmaf(t.y, p, ay);
                az = fmaf(t.z, p, az);
                aw = fmaf(t.w, p, aw);
            }
        }
        int m3 = MOFF3;
#pragma unroll
        for (int i = 0; i < 9; ++i) {
#pragma unroll
            for (int j = i; j < 9; ++j) {
                float p = xr[i] * xr[j];
#pragma unroll
                for (int k = j; k < 9; ++k) {
                    float4 t = T[m3++];
                    float q = p * xr[k];
                    ax = fmaf(t.x, q, ax);
                    ay = fmaf(t.y, q, ay);
                    az = fmaf(t.z, q, az);
                    aw = fmaf(t.w, q, aw);
                }
            }
        }
    } else {
        // ======== LDS variant (R11 walk) ========
#pragma unroll
        for (int i = 0; i < 9; ++i) {
            float q = xr[i];
            ax = fmaf(Tx[i], q, ax);
            ay = fmaf(Ty[i], q, ay);
            az = fmaf(Tz[i], q, az);
            aw = fmaf(Tw[i], q, aw);
        }
        int m2 = 9;
#pragma unroll
        for (int i = 0; i < 9; ++i) {
#pragma unroll
            for (int j = i; j < 9; ++j) {
                float p = xr[i] * xr[j];
                ax = fmaf(Tx[m2], p, ax);
                ay = fmaf(Ty[m2], p, ay);
                az = fmaf(Tz[m2], p, az);
                aw = fmaf(Tw[m2], p, aw);
                ++m2;
            }
        }
        int m3 = 54;
#pragma unroll
        for (int i = 0; i < 9; ++i) {
#pragma unroll
            for (int j = i; j < 9; ++j) {
                float p = xr[i] * xr[j];
#pragma unroll
                for (int k = j; k < 9; ++k) {
                    float q = p * xr[k];
                    ax = fmaf(Tx[m3], q, ax);
                    ay = fmaf(Ty[m3], q, ay);
                    az = fmaf(Tz[m3], q, az);
                    aw = fmaf(Tw[m3], q, aw);
                    ++m3;
                }
            }
        }
    }

    float* o = out + (size_t)b * 512;
    o[c] = ax;
    o[128 + c * 3 + 0] = ay;
    o[128 + c * 3 + 1] = az;
    o[128 + c * 3 + 2] = aw;
}

// ---------------------------------------------------------------------------
extern "C" void kernel_launch(void* const* d_in, const int* in_sizes, int n_in,
                              void* d_out, int out_size, void* d_ws, size_t ws_size,
                              hipStream_t stream) {
    const float* x   = (const float*)d_in[0];
    const float* y   = (const float*)d_in[1];
    const float* U1s = (const float*)d_in[2];
    const float* U2s = (const float*)d_in[3];
    const float* U3s = (const float*)d_in[4];
    const float* W1s = (const float*)d_in[5];
    const float* W2s = (const float*)d_in[6];
    const float* W3s = (const float*)d_in[7];
    const float* U1v = (const float*)d_in[8];
    const float* U2v = (const float*)d_in[9];
    const float* U3v = (const float*)d_in[10];
    const float* W1v = (const float*)d_in[11];
    const float* W2v = (const float*)d_in[12];
    const float* W3v = (const float*)d_in[13];
    float* out = (float*)d_out;

    int*   cnt    = (int*)((char*)d_ws + WS_CNT);
    int*   list   = (int*)((char*)d_ws + WS_LIST);
    float* usym   = (float*)((char*)d_ws + WS_USYM);
    float* tables = (float*)((char*)d_ws + WS_TABLES);

    hipMemsetAsync(d_ws, 0, 64, stream);
    prep_kernel<<<dim3(16 + SYMU_BLOCKS), dim3(256), 0, stream>>>(
        y, cnt, list, U3s, U2s, U3v, U2v, usym);
    build_tables_kernel<<<dim3(NMT, E_N), dim3(128), 0, stream>>>(
        usym, U1s, U1v, W1s, W2s, W3s, W1v, W2v, W3v, tables);
    sc_main_kernel<<<dim3(128, E_N, 4), dim3(256), 0, stream>>>(
        x, cnt, list, tables, out);
}

// Round 16
// 77.199 us; speedup vs baseline: 2.6870x; 2.6870x over previous
//
#include <hip/hip_runtime.h>

#define B_N 4096
#define C_N 128
#define E_N 10

#define NM3 165
#define NM2 45
#define NMT 219           // dense m: deg1 0..8, deg2 9..53, deg3 54..218
#define TSTRIDE 240       // float4 stride per (e,c) table (3840 B)
// 64B-aligned section starts (float4 units) in the padded table:
#define MOFF1 0           // deg1: 0..8
#define MOFF2 12          // deg2: 12..56  (45)
#define MOFF3 60          // deg3: 60..224 (165)
#define LDSPLIT 116       // padded offset where the LDS-staged tail begins
#define NLDS (MOFF3 + NM3 - LDSPLIT)   // 109 staged deg3 monomials

// Usym float-offsets (relative to usym base in ws)
#define OFF_S3 0          // [165][23]
#define OFF_V3 3795       // [165][3][15]
#define OFF_S2 11220      // [45][3]
#define OFF_V2 11355      // [45][12]
#define USYM_FLOATS 11895
#define SYMU_BLOCKS 47    // ceil(11895/256)

// ws byte offsets
#define WS_CNT    0
#define WS_LIST   64
#define WS_USYM   (64 + B_N * E_N * 4)            // 163904
#define WS_TABLES 212992                           // 1024-aligned
// tables bytes: 1280 * 240 * 16 = 4,915,200

__device__ __forceinline__ void unrank3(int m, int& I, int& J, int& K) {
    int n = 0;
    for (int i = 0; i < 9; ++i)
        for (int j = i; j < 9; ++j)
            for (int k = j; k < 9; ++k) {
                if (n == m) { I = i; J = j; K = k; return; }
                ++n;
            }
}
__device__ __forceinline__ void unrank2(int m, int& I, int& J) {
    int n = 0;
    for (int i = 0; i < 9; ++i)
        for (int j = i; j < 9; ++j) {
            if (n == m) { I = i; J = j; return; }
            ++n;
        }
}

// ---------------------------------------------------------------------------
// Kernel 1 (merged prep, R15-proven): blocks 0..15 bucket nodes by element;
// blocks 16..62 symmetrize U into the monomial basis.
// ---------------------------------------------------------------------------
__global__ __launch_bounds__(256) void prep_kernel(
    const float* __restrict__ y, int* __restrict__ cnt, int* __restrict__ list,
    const float* __restrict__ U3s, const float* __restrict__ U2s,
    const float* __restrict__ U3v, const float* __restrict__ U2v,
    float* __restrict__ us)
{
    const int blk = blockIdx.x;
    const int tid = threadIdx.x;
    if (blk < 16) {
        int b = blk * 256 + tid;
        if (b >= B_N) return;
        const float* yb = y + (size_t)b * E_N;
        int e = 0;
#pragma unroll
        for (int j = 1; j < E_N; ++j) e = (yb[j] > 0.5f) ? j : e;
        int pos = atomicAdd(&cnt[e], 1);
        list[e * B_N + pos] = b;
        return;
    }
    int t = (blk - 16) * 256 + tid;
    if (t < 3795) {                      // S3: [165][23]
        int m = t / 23, kk = t - m * 23;
        int i, j, k; unrank3(m, i, j, k);
        float sc = (i == k) ? (1.f / 6.f) : ((i == j || j == k) ? 0.5f : 1.f);
#define U3S(a,b,cc) U3s[(((a)*9+(b))*9+(cc))*23 + kk]
        float v = U3S(i,j,k) + U3S(i,k,j) + U3S(j,i,k) + U3S(j,k,i) + U3S(k,i,j) + U3S(k,j,i);
        us[OFF_S3 + m * 23 + kk] = v * sc;
    } else if (t < 11220) {              // V3: [165][3][15]
        int r = t - 3795;
        int m = r / 45, q = r - m * 45;
        int a = q / 15, kk = q - a * 15;
        int i, j, k; unrank3(m, i, j, k);
        float sc = (i == k) ? (1.f / 6.f) : ((i == j || j == k) ? 0.5f : 1.f);
#define U3V(p,b,cc) U3v[((((a)*9+(p))*9+(b))*9+(cc))*15 + kk]
        float v = U3V(i,j,k) + U3V(i,k,j) + U3V(j,i,k) + U3V(j,k,i) + U3V(k,i,j) + U3V(k,j,i);
        us[OFF_V3 + m * 45 + a * 15 + kk] = v * sc;
    } else if (t < 11355) {              // S2: [45][3]
        int r = t - 11220;
        int m = r / 3, kk = r - m * 3;
        int i, j; unrank2(m, i, j);
        float sc = (i == j) ? 0.5f : 1.f;
        us[OFF_S2 + m * 3 + kk] =
            (U2s[(i * 9 + j) * 3 + kk] + U2s[(j * 9 + i) * 3 + kk]) * sc;
    } else if (t < USYM_FLOATS) {        // V2: [45][12]
        int r = t - 11355;
        int m = r / 12, q = r - m * 12;
        int a = q / 4, kk = q - a * 4;
        int i, j; unrank2(m, i, j);
        float sc = (i == j) ? 0.5f : 1.f;
        us[OFF_V2 + m * 12 + a * 4 + kk] =
            (U2v[((a * 9 + i) * 9 + j) * 4 + kk] + U2v[((a * 9 + j) * 9 + i) * 4 + kk]) * sc;
    }
}

// ---------------------------------------------------------------------------
// Kernel 2 (R15-proven): build per-(e,c) tables, grid (m,e) x threads=c:
// usym reads block-uniform (s_load), W reads coalesced. Padded layout,
// sections 64B-aligned at MOFF1/2/3 for s_load merging in the main kernel.
// ---------------------------------------------------------------------------
__global__ __launch_bounds__(128) void build_tables_kernel(
    const float* __restrict__ usym,
    const float* __restrict__ U1s, const float* __restrict__ U1v,
    const float* __restrict__ W1s, const float* __restrict__ W2s, const float* __restrict__ W3s,
    const float* __restrict__ W1v, const float* __restrict__ W2v, const float* __restrict__ W3v,
    float* __restrict__ tables)
{
    const int m = blockIdx.x;   // 0..218 (dense index)
    const int e = blockIdx.y;   // 0..9
    const int c = threadIdx.x;  // 0..127

    float4 t;
    int moff;
    if (m < 9) {
        moff = MOFF1 + m;
        t.x = U1s[m]      * W1s[e * C_N + c];
        t.y = U1v[m]      * W1v[e * C_N + c];
        t.z = U1v[9 + m]  * W1v[e * C_N + c];
        t.w = U1v[18 + m] * W1v[e * C_N + c];
    } else if (m < 9 + NM2) {
        const int mm = m - 9;
        moff = MOFF2 + mm;
        float s = 0.f;
#pragma unroll
        for (int k = 0; k < 3; ++k)
            s = fmaf(usym[OFF_S2 + mm * 3 + k], W2s[(e * 3 + k) * C_N + c], s);
        t.x = s;
        float tv[3];
#pragma unroll
        for (int a = 0; a < 3; ++a) {
            float sv = 0.f;
#pragma unroll
            for (int k = 0; k < 4; ++k)
                sv = fmaf(usym[OFF_V2 + mm * 12 + a * 4 + k], W2v[(e * 4 + k) * C_N + c], sv);
            tv[a] = sv;
        }
        t.y = tv[0]; t.z = tv[1]; t.w = tv[2];
    } else {
        const int mm = m - (9 + NM2);
        moff = MOFF3 + mm;
        float s = 0.f;
#pragma unroll
        for (int k = 0; k < 23; ++k)
            s = fmaf(usym[OFF_S3 + mm * 23 + k], W3s[(e * 23 + k) * C_N + c], s);
        t.x = s;
        float tv[3];
#pragma unroll
        for (int a = 0; a < 3; ++a) {
            float sv = 0.f;
#pragma unroll
            for (int k = 0; k < 15; ++k)
                sv = fmaf(usym[OFF_V3 + mm * 45 + a * 15 + k], W3v[(e * 15 + k) * C_N + c], sv);
            tv[a] = sv;
        }
        t.y = tv[0]; t.z = tv[1]; t.w = tv[2];
    }
    ((float4*)tables)[(size_t)(e * C_N + c) * TSTRIDE + moff] = t;
}

// ---------------------------------------------------------------------------
// Kernel 3 (R14-proven main, layout-adapted): DUAL-PIPE within-wave split,
// NB=1. Padded offsets 0..115 (deg1+deg2+first-56-deg3) via SMEM lane
// (uniform pointer, ascending 64B-aligned sections -> merged s_load->SGPR);
// padded offsets 116..224 (last 109 deg3) staged once into LDS (1.7 KB b32
// SoA, same-address broadcasts). Single unified walk (NOT two variants --
// R15 showed co-compiled variants blow regalloc to 228 VGPR).
// ---------------------------------------------------------------------------
__global__ __launch_bounds__(256) void sc_main_kernel(
    const float* __restrict__ x,
    const int* __restrict__ cnt, const int* __restrict__ list,
    const float* __restrict__ tables,
    float* __restrict__ out)
{
    const int c     = blockIdx.x;   // 0..127
    const int e     = blockIdx.y;   // 0..9
    const int chunk = blockIdx.z;   // 0..3

    const int n = cnt[e];
    if (chunk * 256 >= n) return;   // block-uniform exit (pre-barrier)

    __shared__ float Tx[NLDS], Ty[NLDS], Tz[NLDS], Tw[NLDS];
    const int tid = threadIdx.x;

    const float4* __restrict__ T =
        (const float4*)tables + (size_t)(e * C_N + c) * TSTRIDE;   // block-uniform

    if (tid < NLDS) {
        float4 t = T[LDSPLIT + tid];
        Tx[tid] = t.x; Ty[tid] = t.y; Tz[tid] = t.z; Tw[tid] = t.w;
    }
    __syncthreads();

    const int idx = chunk * 256 + tid;
    if (idx >= n) return;           // no barriers after this point
    const int b = list[e * B_N + idx];

    const float* xp = x + ((size_t)b * C_N + c) * 9;
    float xr[9];
#pragma unroll
    for (int i = 0; i < 9; ++i) xr[i] = xp[i];

    float ax = 0.f, ay = 0.f, az = 0.f, aw = 0.f;

    // ---- degree 1: T[0..8] (SMEM) ----
#pragma unroll
    for (int i = 0; i < 9; ++i) {
        float4 t = T[MOFF1 + i];
        float q = xr[i];
        ax = fmaf(t.x, q, ax);
        ay = fmaf(t.y, q, ay);
        az = fmaf(t.z, q, az);
        aw = fmaf(t.w, q, aw);
    }

    // ---- degree 2: T[12..56] (SMEM), ascending pair order ----
    int m2 = MOFF2;
#pragma unroll
    for (int i = 0; i < 9; ++i) {
#pragma unroll
        for (int j = i; j < 9; ++j) {
            float4 t = T[m2++];
            float p = xr[i] * xr[j];
            ax = fmaf(t.x, p, ax);
            ay = fmaf(t.y, p, ay);
            az = fmaf(t.z, p, az);
            aw = fmaf(t.w, p, aw);
        }
    }

    // ---- degree 3: padded 60..224 ascending; <116 SMEM, >=116 LDS ----
    int m3 = MOFF3;
#pragma unroll
    for (int i = 0; i < 9; ++i) {
#pragma unroll
        for (int j = i; j < 9; ++j) {
            float p = xr[i] * xr[j];
#pragma unroll
            for (int k = j; k < 9; ++k) {
                float q = p * xr[k];
                if (m3 < LDSPLIT) {         // compile-time after full unroll
                    float4 t = T[m3];
                    ax = fmaf(t.x, q, ax);
                    ay = fmaf(t.y, q, ay);
                    az = fmaf(t.z, q, az);
                    aw = fmaf(t.w, q, aw);
                } else {
                    int s = m3 - LDSPLIT;
                    ax = fmaf(Tx[s], q, ax);
                    ay = fmaf(Ty[s], q, ay);
                    az = fmaf(Tz[s], q, az);
                    aw = fmaf(Tw[s], q, aw);
                }
                ++m3;
            }
        }
    }

    float* o = out + (size_t)b * 512;
    o[c] = ax;
    o[128 + c * 3 + 0] = ay;
    o[128 + c * 3 + 1] = az;
    o[128 + c * 3 + 2] = aw;
}

// ---------------------------------------------------------------------------
extern "C" void kernel_launch(void* const* d_in, const int* in_sizes, int n_in,
                              void* d_out, int out_size, void* d_ws, size_t ws_size,
                              hipStream_t stream) {
    const float* x   = (const float*)d_in[0];
    const float* y   = (const float*)d_in[1];
    const float* U1s = (const float*)d_in[2];
    const float* U2s = (const float*)d_in[3];
    const float* U3s = (const float*)d_in[4];
    const float* W1s = (const float*)d_in[5];
    const float* W2s = (const float*)d_in[6];
    const float* W3s = (const float*)d_in[7];
    const float* U1v = (const float*)d_in[8];
    const float* U2v = (const float*)d_in[9];
    const float* U3v = (const float*)d_in[10];
    const float* W1v = (const float*)d_in[11];
    const float* W2v = (const float*)d_in[12];
    const float* W3v = (const float*)d_in[13];
    float* out = (float*)d_out;

    int*   cnt    = (int*)((char*)d_ws + WS_CNT);
    int*   list   = (int*)((char*)d_ws + WS_LIST);
    float* usym   = (float*)((char*)d_ws + WS_USYM);
    float* tables = (float*)((char*)d_ws + WS_TABLES);

    hipMemsetAsync(d_ws, 0, 64, stream);
    prep_kernel<<<dim3(16 + SYMU_BLOCKS), dim3(256), 0, stream>>>(
        y, cnt, list, U3s, U2s, U3v, U2v, usym);
    build_tables_kernel<<<dim3(NMT, E_N), dim3(128), 0, stream>>>(
        usym, U1s, U1v, W1s, W2s, W3s, W1v, W2v, W3v, tables);
    sc_main_kernel<<<dim3(128, E_N, 4), dim3(256), 0, stream>>>(
        x, cnt, list, tables, out);
}

// Round 17
// 65.390 us; speedup vs baseline: 3.1723x; 1.1806x over previous
//
#include <hip/hip_runtime.h>

#define B_N 4096
#define C_N 128
#define E_N 10

#define NM3 165
#define NM2 45
#define NMT 219           // dense m: deg1 0..8, deg2 9..53, deg3 54..218
#define MSPLIT 110        // m < MSPLIT via SMEM lane; m >= MSPLIT via LDS
#define NLDS (NMT - MSPLIT)   // 109 staged deg3 monomials
#define TSTRIDE 224       // float4 stride per (e,c) table (3584 B), dense

// Usym float-offsets (relative to usym base in ws)
#define OFF_S3 0          // [165][23]
#define OFF_V3 3795       // [165][3][15]
#define OFF_S2 11220      // [45][3]
#define OFF_V2 11355      // [45][12]
#define USYM_FLOATS 11895
#define SYMU_BLOCKS 47    // ceil(11895/256)

// ws byte offsets
#define WS_CNT    0
#define WS_LIST   64
#define WS_USYM   (64 + B_N * E_N * 4)            // 163904
#define WS_TABLES 212992                           // 1024-aligned
// tables bytes: 1280 * 224 * 16 = 4,587,520

__device__ __forceinline__ void unrank3(int m, int& I, int& J, int& K) {
    int n = 0;
    for (int i = 0; i < 9; ++i)
        for (int j = i; j < 9; ++j)
            for (int k = j; k < 9; ++k) {
                if (n == m) { I = i; J = j; K = k; return; }
                ++n;
            }
}
__device__ __forceinline__ void unrank2(int m, int& I, int& J) {
    int n = 0;
    for (int i = 0; i < 9; ++i)
        for (int j = i; j < 9; ++j) {
            if (n == m) { I = i; J = j; return; }
            ++n;
        }
}

// ---------------------------------------------------------------------------
// Kernel 1 (merged prep, R15-proven): blocks 0..15 bucket nodes by element;
// blocks 16..62 symmetrize U into the monomial basis.
// ---------------------------------------------------------------------------
__global__ __launch_bounds__(256) void prep_kernel(
    const float* __restrict__ y, int* __restrict__ cnt, int* __restrict__ list,
    const float* __restrict__ U3s, const float* __restrict__ U2s,
    const float* __restrict__ U3v, const float* __restrict__ U2v,
    float* __restrict__ us)
{
    const int blk = blockIdx.x;
    const int tid = threadIdx.x;
    if (blk < 16) {
        int b = blk * 256 + tid;
        if (b >= B_N) return;
        const float* yb = y + (size_t)b * E_N;
        int e = 0;
#pragma unroll
        for (int j = 1; j < E_N; ++j) e = (yb[j] > 0.5f) ? j : e;
        int pos = atomicAdd(&cnt[e], 1);
        list[e * B_N + pos] = b;
        return;
    }
    int t = (blk - 16) * 256 + tid;
    if (t < 3795) {                      // S3: [165][23]
        int m = t / 23, kk = t - m * 23;
        int i, j, k; unrank3(m, i, j, k);
        float sc = (i == k) ? (1.f / 6.f) : ((i == j || j == k) ? 0.5f : 1.f);
#define U3S(a,b,cc) U3s[(((a)*9+(b))*9+(cc))*23 + kk]
        float v = U3S(i,j,k) + U3S(i,k,j) + U3S(j,i,k) + U3S(j,k,i) + U3S(k,i,j) + U3S(k,j,i);
        us[OFF_S3 + m * 23 + kk] = v * sc;
    } else if (t < 11220) {              // V3: [165][3][15]
        int r = t - 3795;
        int m = r / 45, q = r - m * 45;
        int a = q / 15, kk = q - a * 15;
        int i, j, k; unrank3(m, i, j, k);
        float sc = (i == k) ? (1.f / 6.f) : ((i == j || j == k) ? 0.5f : 1.f);
#define U3V(p,b,cc) U3v[((((a)*9+(p))*9+(b))*9+(cc))*15 + kk]
        float v = U3V(i,j,k) + U3V(i,k,j) + U3V(j,i,k) + U3V(j,k,i) + U3V(k,i,j) + U3V(k,j,i);
        us[OFF_V3 + m * 45 + a * 15 + kk] = v * sc;
    } else if (t < 11355) {              // S2: [45][3]
        int r = t - 11220;
        int m = r / 3, kk = r - m * 3;
        int i, j; unrank2(m, i, j);
        float sc = (i == j) ? 0.5f : 1.f;
        us[OFF_S2 + m * 3 + kk] =
            (U2s[(i * 9 + j) * 3 + kk] + U2s[(j * 9 + i) * 3 + kk]) * sc;
    } else if (t < USYM_FLOATS) {        // V2: [45][12]
        int r = t - 11355;
        int m = r / 12, q = r - m * 12;
        int a = q / 4, kk = q - a * 4;
        int i, j; unrank2(m, i, j);
        float sc = (i == j) ? 0.5f : 1.f;
        us[OFF_V2 + m * 12 + a * 4 + kk] =
            (U2v[((a * 9 + i) * 9 + j) * 4 + kk] + U2v[((a * 9 + j) * 9 + i) * 4 + kk]) * sc;
    }
}

// ---------------------------------------------------------------------------
// Kernel 2 (R15-proven structure, dense layout): grid (m,e) x threads=c:
// usym reads block-uniform (s_load), W reads coalesced across lanes.
// Table[(e*128+c)*224 + m] = float4(s, v0, v1, v2), m dense 0..218.
// ---------------------------------------------------------------------------
__global__ __launch_bounds__(128) void build_tables_kernel(
    const float* __restrict__ usym,
    const float* __restrict__ U1s, const float* __restrict__ U1v,
    const float* __restrict__ W1s, const float* __restrict__ W2s, const float* __restrict__ W3s,
    const float* __restrict__ W1v, const float* __restrict__ W2v, const float* __restrict__ W3v,
    float* __restrict__ tables)
{
    const int m = blockIdx.x;   // 0..218 (dense index)
    const int e = blockIdx.y;   // 0..9
    const int c = threadIdx.x;  // 0..127

    float4 t;
    if (m < 9) {
        t.x = U1s[m]      * W1s[e * C_N + c];
        t.y = U1v[m]      * W1v[e * C_N + c];
        t.z = U1v[9 + m]  * W1v[e * C_N + c];
        t.w = U1v[18 + m] * W1v[e * C_N + c];
    } else if (m < 9 + NM2) {
        const int mm = m - 9;
        float s = 0.f;
#pragma unroll
        for (int k = 0; k < 3; ++k)
            s = fmaf(usym[OFF_S2 + mm * 3 + k], W2s[(e * 3 + k) * C_N + c], s);
        t.x = s;
        float tv[3];
#pragma unroll
        for (int a = 0; a < 3; ++a) {
            float sv = 0.f;
#pragma unroll
            for (int k = 0; k < 4; ++k)
                sv = fmaf(usym[OFF_V2 + mm * 12 + a * 4 + k], W2v[(e * 4 + k) * C_N + c], sv);
            tv[a] = sv;
        }
        t.y = tv[0]; t.z = tv[1]; t.w = tv[2];
    } else {
        const int mm = m - (9 + NM2);
        float s = 0.f;
#pragma unroll
        for (int k = 0; k < 23; ++k)
            s = fmaf(usym[OFF_S3 + mm * 23 + k], W3s[(e * 23 + k) * C_N + c], s);
        t.x = s;
        float tv[3];
#pragma unroll
        for (int a = 0; a < 3; ++a) {
            float sv = 0.f;
#pragma unroll
            for (int k = 0; k < 15; ++k)
                sv = fmaf(usym[OFF_V3 + mm * 45 + a * 15 + k], W3v[(e * 15 + k) * C_N + c], sv);
            tv[a] = sv;
        }
        t.y = tv[0]; t.z = tv[1]; t.w = tv[2];
    }
    ((float4*)tables)[(size_t)(e * C_N + c) * TSTRIDE + m] = t;
}

// ---------------------------------------------------------------------------
// Kernel 3: R14's dense-layout dual-pipe main + ASYNC STAGING (T14): the
// LDS-tail global load issues first (registers), the SMEM deg1+deg2 phases
// run while it flies, then ds_write + barrier, then the deg3 nest (first 56
// via SMEM, last 109 via LDS). Staging latency hides under SMEM work and
// blocks enter the LDS phase staggered. NB=1 (the only non-spilling width);
// single unified walk (R15 showed dual variants blow regalloc).
// ---------------------------------------------------------------------------
__global__ __launch_bounds__(256) void sc_main_kernel(
    const float* __restrict__ x,
    const int* __restrict__ cnt, const int* __restrict__ list,
    const float* __restrict__ tables,
    float* __restrict__ out)
{
    const int c     = blockIdx.x;   // 0..127
    const int e     = blockIdx.y;   // 0..9
    const int chunk = blockIdx.z;   // 0..3

    const int n = cnt[e];
    if (chunk * 256 >= n) return;   // block-uniform exit (pre-barrier)

    __shared__ float Tx[NLDS], Ty[NLDS], Tz[NLDS], Tw[NLDS];
    const int tid = threadIdx.x;

    const float4* __restrict__ T =
        (const float4*)tables + (size_t)(e * C_N + c) * TSTRIDE;   // block-uniform

    // ---- issue LDS-tail staging load early (plain global -> regs) ----
    float4 stg = make_float4(0.f, 0.f, 0.f, 0.f);
    if (tid < NLDS) stg = T[MSPLIT + tid];

    const int idx = chunk * 256 + tid;
    const bool active = idx < n;
    const int cl = active ? idx : n - 1;
    const int b = list[e * B_N + cl];

    float xr[9];
    float ax = 0.f, ay = 0.f, az = 0.f, aw = 0.f;

    if (active) {
        const float* xp = x + ((size_t)b * C_N + c) * 9;
#pragma unroll
        for (int i = 0; i < 9; ++i) xr[i] = xp[i];

        // ---- degree 1: m = 0..8 (SMEM) ----
#pragma unroll
        for (int i = 0; i < 9; ++i) {
            float4 t = T[i];
            float q = xr[i];
            ax = fmaf(t.x, q, ax);
            ay = fmaf(t.y, q, ay);
            az = fmaf(t.z, q, az);
            aw = fmaf(t.w, q, aw);
        }

        // ---- degree 2: m = 9..53 (SMEM), ascending pair order ----
        int m2 = 9;
#pragma unroll
        for (int i = 0; i < 9; ++i) {
#pragma unroll
            for (int j = i; j < 9; ++j) {
                float4 t = T[m2++];
                float p = xr[i] * xr[j];
                ax = fmaf(t.x, p, ax);
                ay = fmaf(t.y, p, ay);
                az = fmaf(t.z, p, az);
                aw = fmaf(t.w, p, aw);
            }
        }
    }

    // ---- write staged tail to LDS, then barrier ----
    if (tid < NLDS) {
        Tx[tid] = stg.x; Ty[tid] = stg.y; Tz[tid] = stg.z; Tw[tid] = stg.w;
    }
    __syncthreads();

    if (!active) return;

    // ---- degree 3: m = 54..218 ascending; m<110 SMEM, m>=110 LDS ----
    int m3 = 54;
#pragma unroll
    for (int i = 0; i < 9; ++i) {
#pragma unroll
        for (int j = i; j < 9; ++j) {
            float p = xr[i] * xr[j];
#pragma unroll
            for (int k = j; k < 9; ++k) {
                float q = p * xr[k];
                if (m3 < MSPLIT) {          // compile-time after full unroll
                    float4 t = T[m3];
                    ax = fmaf(t.x, q, ax);
                    ay = fmaf(t.y, q, ay);
                    az = fmaf(t.z, q, az);
                    aw = fmaf(t.w, q, aw);
                } else {
                    int s = m3 - MSPLIT;
                    ax = fmaf(Tx[s], q, ax);
                    ay = fmaf(Ty[s], q, ay);
                    az = fmaf(Tz[s], q, az);
                    aw = fmaf(Tw[s], q, aw);
                }
                ++m3;
            }
        }
    }

    float* o = out + (size_t)b * 512;
    o[c] = ax;
    o[128 + c * 3 + 0] = ay;
    o[128 + c * 3 + 1] = az;
    o[128 + c * 3 + 2] = aw;
}

// ---------------------------------------------------------------------------
extern "C" void kernel_launch(void* const* d_in, const int* in_sizes, int n_in,
                              void* d_out, int out_size, void* d_ws, size_t ws_size,
                              hipStream_t stream) {
    const float* x   = (const float*)d_in[0];
    const float* y   = (const float*)d_in[1];
    const float* U1s = (const float*)d_in[2];
    const float* U2s = (const float*)d_in[3];
    const float* U3s = (const float*)d_in[4];
    const float* W1s = (const float*)d_in[5];
    const float* W2s = (const float*)d_in[6];
    const float* W3s = (const float*)d_in[7];
    const float* U1v = (const float*)d_in[8];
    const float* U2v = (const float*)d_in[9];
    const float* U3v = (const float*)d_in[10];
    const float* W1v = (const float*)d_in[11];
    const float* W2v = (const float*)d_in[12];
    const float* W3v = (const float*)d_in[13];
    float* out = (float*)d_out;

    int*   cnt    = (int*)((char*)d_ws + WS_CNT);
    int*   list   = (int*)((char*)d_ws + WS_LIST);
    float* usym   = (float*)((char*)d_ws + WS_USYM);
    float* tables = (float*)((char*)d_ws + WS_TABLES);

    hipMemsetAsync(d_ws, 0, 64, stream);
    prep_kernel<<<dim3(16 + SYMU_BLOCKS), dim3(256), 0, stream>>>(
        y, cnt, list, U3s, U2s, U3v, U2v, usym);
    build_tables_kernel<<<dim3(NMT, E_N), dim3(128), 0, stream>>>(
        usym, U1s, U1v, W1s, W2s, W3s, W1v, W2v, W3v, tables);
    sc_main_kernel<<<dim3(128, E_N, 4), dim3(256), 0, stream>>>(
        x, cnt, list, tables, out);
}

// Round 18
// 65.175 us; speedup vs baseline: 3.1827x; 1.0033x over previous
//
#include <hip/hip_runtime.h>

#define B_N 4096
#define C_N 128
#define E_N 10

#define NM3 165
#define NM2 45
#define NMT 219           // dense m: deg1 0..8, deg2 9..53, deg3 54..218
#define MSPLIT 110        // m < MSPLIT via SMEM lane; m >= MSPLIT via LDS
#define NLDS (NMT - MSPLIT)   // 109 staged deg3 monomials
#define TSTRIDE 224       // uint2 stride per (e,c) table (1792 B), dense

// Usym float-offsets (relative to usym base in ws)
#define OFF_S3 0          // [165][23]
#define OFF_V3 3795       // [165][3][15]
#define OFF_S2 11220      // [45][3]
#define OFF_V2 11355      // [45][12]
#define USYM_FLOATS 11895
#define SYMU_BLOCKS 47    // ceil(11895/256)

// ws byte offsets
#define WS_CNT    0
#define WS_LIST   64
#define WS_USYM   (64 + B_N * E_N * 4)            // 163904
#define WS_TABLES 212992  // 1024-aligned; tables: 1280 * 224 * 8 = 2,293,760 B

__device__ __forceinline__ void unrank3(int m, int& I, int& J, int& K) {
    int n = 0;
    for (int i = 0; i < 9; ++i)
        for (int j = i; j < 9; ++j)
            for (int k = j; k < 9; ++k) {
                if (n == m) { I = i; J = j; K = k; return; }
                ++n;
            }
}
__device__ __forceinline__ void unrank2(int m, int& I, int& J) {
    int n = 0;
    for (int i = 0; i < 9; ++i)
        for (int j = i; j < 9; ++j) {
            if (n == m) { I = i; J = j; return; }
            ++n;
        }
}

// pack two floats as bf16 pair (RNE): low element a, high element b
__device__ __forceinline__ unsigned pack_bf2(float a, float b) {
    unsigned ua = __float_as_uint(a), ub = __float_as_uint(b);
    ua += 0x7fff + ((ua >> 16) & 1);
    ub += 0x7fff + ((ub >> 16) & 1);
    return (ua >> 16) | (ub & 0xffff0000u);
}
// unpack: lo = bits<<16, hi = bits&0xffff0000
__device__ __forceinline__ void unpk_bf2(unsigned u, float& lo, float& hi) {
    lo = __uint_as_float(u << 16);
    hi = __uint_as_float(u & 0xffff0000u);
}

// ---------------------------------------------------------------------------
// Kernel 1 (merged prep, R15-proven): blocks 0..15 bucket nodes by element;
// blocks 16..62 symmetrize U into the monomial basis.
// ---------------------------------------------------------------------------
__global__ __launch_bounds__(256) void prep_kernel(
    const float* __restrict__ y, int* __restrict__ cnt, int* __restrict__ list,
    const float* __restrict__ U3s, const float* __restrict__ U2s,
    const float* __restrict__ U3v, const float* __restrict__ U2v,
    float* __restrict__ us)
{
    const int blk = blockIdx.x;
    const int tid = threadIdx.x;
    if (blk < 16) {
        int b = blk * 256 + tid;
        if (b >= B_N) return;
        const float* yb = y + (size_t)b * E_N;
        int e = 0;
#pragma unroll
        for (int j = 1; j < E_N; ++j) e = (yb[j] > 0.5f) ? j : e;
        int pos = atomicAdd(&cnt[e], 1);
        list[e * B_N + pos] = b;
        return;
    }
    int t = (blk - 16) * 256 + tid;
    if (t < 3795) {                      // S3: [165][23]
        int m = t / 23, kk = t - m * 23;
        int i, j, k; unrank3(m, i, j, k);
        float sc = (i == k) ? (1.f / 6.f) : ((i == j || j == k) ? 0.5f : 1.f);
#define U3S(a,b,cc) U3s[(((a)*9+(b))*9+(cc))*23 + kk]
        float v = U3S(i,j,k) + U3S(i,k,j) + U3S(j,i,k) + U3S(j,k,i) + U3S(k,i,j) + U3S(k,j,i);
        us[OFF_S3 + m * 23 + kk] = v * sc;
    } else if (t < 11220) {              // V3: [165][3][15]
        int r = t - 3795;
        int m = r / 45, q = r - m * 45;
        int a = q / 15, kk = q - a * 15;
        int i, j, k; unrank3(m, i, j, k);
        float sc = (i == k) ? (1.f / 6.f) : ((i == j || j == k) ? 0.5f : 1.f);
#define U3V(p,b,cc) U3v[((((a)*9+(p))*9+(b))*9+(cc))*15 + kk]
        float v = U3V(i,j,k) + U3V(i,k,j) + U3V(j,i,k) + U3V(j,k,i) + U3V(k,i,j) + U3V(k,j,i);
        us[OFF_V3 + m * 45 + a * 15 + kk] = v * sc;
    } else if (t < 11355) {              // S2: [45][3]
        int r = t - 11220;
        int m = r / 3, kk = r - m * 3;
        int i, j; unrank2(m, i, j);
        float sc = (i == j) ? 0.5f : 1.f;
        us[OFF_S2 + m * 3 + kk] =
            (U2s[(i * 9 + j) * 3 + kk] + U2s[(j * 9 + i) * 3 + kk]) * sc;
    } else if (t < USYM_FLOATS) {        // V2: [45][12]
        int r = t - 11355;
        int m = r / 12, q = r - m * 12;
        int a = q / 4, kk = q - a * 4;
        int i, j; unrank2(m, i, j);
        float sc = (i == j) ? 0.5f : 1.f;
        us[OFF_V2 + m * 12 + a * 4 + kk] =
            (U2v[((a * 9 + i) * 9 + j) * 4 + kk] + U2v[((a * 9 + j) * 9 + i) * 4 + kk]) * sc;
    }
}

// ---------------------------------------------------------------------------
// Kernel 2 (R15-proven structure, dense layout, bf16-packed output):
// grid (m,e) x threads=c; usym reads block-uniform (s_load), W coalesced.
// Table[(e*128+c)*224 + m] = uint2{ pack(s,v0), pack(v1,v2) }.
// ---------------------------------------------------------------------------
__global__ __launch_bounds__(128) void build_tables_kernel(
    const float* __restrict__ usym,
    const float* __restrict__ U1s, const float* __restrict__ U1v,
    const float* __restrict__ W1s, const float* __restrict__ W2s, const float* __restrict__ W3s,
    const float* __restrict__ W1v, const float* __restrict__ W2v, const float* __restrict__ W3v,
    unsigned* __restrict__ tables)
{
    const int m = blockIdx.x;   // 0..218 (dense index)
    const int e = blockIdx.y;   // 0..9
    const int c = threadIdx.x;  // 0..127

    float4 t;
    if (m < 9) {
        t.x = U1s[m]      * W1s[e * C_N + c];
        t.y = U1v[m]      * W1v[e * C_N + c];
        t.z = U1v[9 + m]  * W1v[e * C_N + c];
        t.w = U1v[18 + m] * W1v[e * C_N + c];
    } else if (m < 9 + NM2) {
        const int mm = m - 9;
        float s = 0.f;
#pragma unroll
        for (int k = 0; k < 3; ++k)
            s = fmaf(usym[OFF_S2 + mm * 3 + k], W2s[(e * 3 + k) * C_N + c], s);
        t.x = s;
        float tv[3];
#pragma unroll
        for (int a = 0; a < 3; ++a) {
            float sv = 0.f;
#pragma unroll
            for (int k = 0; k < 4; ++k)
                sv = fmaf(usym[OFF_V2 + mm * 12 + a * 4 + k], W2v[(e * 4 + k) * C_N + c], sv);
            tv[a] = sv;
        }
        t.y = tv[0]; t.z = tv[1]; t.w = tv[2];
    } else {
        const int mm = m - (9 + NM2);
        float s = 0.f;
#pragma unroll
        for (int k = 0; k < 23; ++k)
            s = fmaf(usym[OFF_S3 + mm * 23 + k], W3s[(e * 23 + k) * C_N + c], s);
        t.x = s;
        float tv[3];
#pragma unroll
        for (int a = 0; a < 3; ++a) {
            float sv = 0.f;
#pragma unroll
            for (int k = 0; k < 15; ++k)
                sv = fmaf(usym[OFF_V3 + mm * 45 + a * 15 + k], W3v[(e * 15 + k) * C_N + c], sv);
            tv[a] = sv;
        }
        t.y = tv[0]; t.z = tv[1]; t.w = tv[2];
    }
    ((uint2*)tables)[(size_t)(e * C_N + c) * TSTRIDE + m] =
        make_uint2(pack_bf2(t.x, t.y), pack_bf2(t.z, t.w));
}

// ---------------------------------------------------------------------------
// Kernel 3: R17's async-staged dual-pipe main, bf16-packed coefficients.
// SMEM lane now 14 s_load_x16 batches (was 28); LDS lane 218 b32 reads
// (was 436); unpack = shift/and pairs. NB=1, single unified walk.
// ---------------------------------------------------------------------------
__global__ __launch_bounds__(256) void sc_main_kernel(
    const float* __restrict__ x,
    const int* __restrict__ cnt, const int* __restrict__ list,
    const unsigned* __restrict__ tables,
    float* __restrict__ out)
{
    const int c     = blockIdx.x;   // 0..127
    const int e     = blockIdx.y;   // 0..9
    const int chunk = blockIdx.z;   // 0..3

    const int n = cnt[e];
    if (chunk * 256 >= n) return;   // block-uniform exit (pre-barrier)

    __shared__ unsigned P0[NLDS], P1[NLDS];
    const int tid = threadIdx.x;

    const uint2* __restrict__ T =
        (const uint2*)tables + (size_t)(e * C_N + c) * TSTRIDE;   // block-uniform

    // ---- issue LDS-tail staging load early (plain global -> regs) ----
    uint2 stg = make_uint2(0u, 0u);
    if (tid < NLDS) stg = T[MSPLIT + tid];

    const int idx = chunk * 256 + tid;
    const bool active = idx < n;
    const int cl = active ? idx : n - 1;
    const int b = list[e * B_N + cl];

    float xr[9];
    float ax = 0.f, ay = 0.f, az = 0.f, aw = 0.f;

    if (active) {
        const float* xp = x + ((size_t)b * C_N + c) * 9;
#pragma unroll
        for (int i = 0; i < 9; ++i) xr[i] = xp[i];

        // ---- degree 1: m = 0..8 (SMEM) ----
#pragma unroll
        for (int i = 0; i < 9; ++i) {
            uint2 t = T[i];
            float s, v0, v1, v2;
            unpk_bf2(t.x, s, v0);
            unpk_bf2(t.y, v1, v2);
            float q = xr[i];
            ax = fmaf(s,  q, ax);
            ay = fmaf(v0, q, ay);
            az = fmaf(v1, q, az);
            aw = fmaf(v2, q, aw);
        }

        // ---- degree 2: m = 9..53 (SMEM), ascending pair order ----
        int m2 = 9;
#pragma unroll
        for (int i = 0; i < 9; ++i) {
#pragma unroll
            for (int j = i; j < 9; ++j) {
                uint2 t = T[m2++];
                float s, v0, v1, v2;
                unpk_bf2(t.x, s, v0);
                unpk_bf2(t.y, v1, v2);
                float p = xr[i] * xr[j];
                ax = fmaf(s,  p, ax);
                ay = fmaf(v0, p, ay);
                az = fmaf(v1, p, az);
                aw = fmaf(v2, p, aw);
            }
        }
    }

    // ---- write staged tail to LDS, then barrier ----
    if (tid < NLDS) { P0[tid] = stg.x; P1[tid] = stg.y; }
    __syncthreads();

    if (!active) return;

    // ---- degree 3: m = 54..218 ascending; m<110 SMEM, m>=110 LDS ----
    int m3 = 54;
#pragma unroll
    for (int i = 0; i < 9; ++i) {
#pragma unroll
        for (int j = i; j < 9; ++j) {
            float p = xr[i] * xr[j];
#pragma unroll
            for (int k = j; k < 9; ++k) {
                float q = p * xr[k];
                float s, v0, v1, v2;
                if (m3 < MSPLIT) {          // compile-time after full unroll
                    uint2 t = T[m3];
                    unpk_bf2(t.x, s, v0);
                    unpk_bf2(t.y, v1, v2);
                } else {
                    int si = m3 - MSPLIT;
                    unpk_bf2(P0[si], s, v0);
                    unpk_bf2(P1[si], v1, v2);
                }
                ax = fmaf(s,  q, ax);
                ay = fmaf(v0, q, ay);
                az = fmaf(v1, q, az);
                aw = fmaf(v2, q, aw);
                ++m3;
            }
        }
    }

    float* o = out + (size_t)b * 512;
    o[c] = ax;
    o[128 + c * 3 + 0] = ay;
    o[128 + c * 3 + 1] = az;
    o[128 + c * 3 + 2] = aw;
}

// ---------------------------------------------------------------------------
extern "C" void kernel_launch(void* const* d_in, const int* in_sizes, int n_in,
                              void* d_out, int out_size, void* d_ws, size_t ws_size,
                              hipStream_t stream) {
    const float* x   = (const float*)d_in[0];
    const float* y   = (const float*)d_in[1];
    const float* U1s = (const float*)d_in[2];
    const float* U2s = (const float*)d_in[3];
    const float* U3s = (const float*)d_in[4];
    const float* W1s = (const float*)d_in[5];
    const float* W2s = (const float*)d_in[6];
    const float* W3s = (const float*)d_in[7];
    const float* U1v = (const float*)d_in[8];
    const float* U2v = (const float*)d_in[9];
    const float* U3v = (const float*)d_in[10];
    const float* W1v = (const float*)d_in[11];
    const float* W2v = (const float*)d_in[12];
    const float* W3v = (const float*)d_in[13];
    float* out = (float*)d_out;

    int*      cnt    = (int*)((char*)d_ws + WS_CNT);
    int*      list   = (int*)((char*)d_ws + WS_LIST);
    float*    usym   = (float*)((char*)d_ws + WS_USYM);
    unsigned* tables = (unsigned*)((char*)d_ws + WS_TABLES);

    hipMemsetAsync(d_ws, 0, 64, stream);
    prep_kernel<<<dim3(16 + SYMU_BLOCKS), dim3(256), 0, stream>>>(
        y, cnt, list, U3s, U2s, U3v, U2v, usym);
    build_tables_kernel<<<dim3(NMT, E_N), dim3(128), 0, stream>>>(
        usym, U1s, U1v, W1s, W2s, W3s, W1v, W2v, W3v, tables);
    sc_main_kernel<<<dim3(128, E_N, 4), dim3(256), 0, stream>>>(
        x, cnt, list, tables, out);
}